// Round 1
// baseline (723.864 us; speedup 1.0000x reference)
//
#include <hip/hip_runtime.h>
#include <hip/hip_bf16.h>
#include <math.h>

#define IN_DIM 512
#define H1     128
#define ZD     64

// ---------------------------------------------------------------------------
// encode: Z = relu(X @ W) @ W2    (fp32, vector-FMA; no fp32 MFMA on CDNA4)
// block = 256 threads (4 waves), BM = 64 rows per block.
// Step 1: h[64][128] = relu(Xtile @ W), K=512 tiled by 32, LDS-staged.
// Step 2: z[64][64]  = h @ W2, h kept transposed in LDS.
// ---------------------------------------------------------------------------
__global__ __launch_bounds__(256, 4) void encode_kernel(
    const float* __restrict__ X, const float* __restrict__ W,
    const float* __restrict__ W2, float* __restrict__ Z, int N)
{
    __shared__ union {
        struct {
            float xt[32][68];   // [k][row], +4 pad: conflict-lite writes, aligned b128 reads
            float wt[32][128];  // [k][col]
        } s1;
        float ht[128][64];      // transposed h: ht[col][row]
    } sm;

    const int tid = threadIdx.x;
    const int tx  = tid & 31;   // 0..31
    const int ty  = tid >> 5;   // 0..7
    const int row0 = blockIdx.x * 64;

    float acc[8][4];
    #pragma unroll
    for (int i = 0; i < 8; ++i)
        #pragma unroll
        for (int j = 0; j < 4; ++j) acc[i][j] = 0.f;

    for (int k0 = 0; k0 < IN_DIM; k0 += 32) {
        // stage X tile (transposed): 64 rows x 32 k  = 512 float4 loads
        #pragma unroll
        for (int t = 0; t < 2; ++t) {
            int idx = tid + t * 256;        // 0..511
            int row = idx >> 3;
            int c4  = idx & 7;
            float4 v = make_float4(0.f, 0.f, 0.f, 0.f);
            int gr = row0 + row;
            if (gr < N)
                v = *(const float4*)&X[(size_t)gr * IN_DIM + k0 + c4 * 4];
            sm.s1.xt[c4 * 4 + 0][row] = v.x;
            sm.s1.xt[c4 * 4 + 1][row] = v.y;
            sm.s1.xt[c4 * 4 + 2][row] = v.z;
            sm.s1.xt[c4 * 4 + 3][row] = v.w;
        }
        // stage W tile: 32 k x 128 cols = 1024 float4 loads
        #pragma unroll
        for (int t = 0; t < 4; ++t) {
            int idx = tid + t * 256;        // 0..1023
            int kk = idx >> 5;
            int c4 = idx & 31;
            *(float4*)&sm.s1.wt[kk][c4 * 4] =
                *(const float4*)&W[(size_t)(k0 + kk) * H1 + c4 * 4];
        }
        __syncthreads();

        #pragma unroll
        for (int k = 0; k < 32; ++k) {
            float4 a0 = *(const float4*)&sm.s1.xt[k][ty * 8];
            float4 a1 = *(const float4*)&sm.s1.xt[k][ty * 8 + 4];
            float4 b  = *(const float4*)&sm.s1.wt[k][tx * 4];
            float a[8] = {a0.x, a0.y, a0.z, a0.w, a1.x, a1.y, a1.z, a1.w};
            float bb[4] = {b.x, b.y, b.z, b.w};
            #pragma unroll
            for (int i = 0; i < 8; ++i)
                #pragma unroll
                for (int j = 0; j < 4; ++j)
                    acc[i][j] = fmaf(a[i], bb[j], acc[i][j]);
        }
        __syncthreads();
    }

    // relu + store h transposed into LDS: ht[c][r], c = tx*4+j, r = ty*8+i
    #pragma unroll
    for (int j = 0; j < 4; ++j) {
        int c = tx * 4 + j;
        float4 lo = make_float4(fmaxf(acc[0][j], 0.f), fmaxf(acc[1][j], 0.f),
                                fmaxf(acc[2][j], 0.f), fmaxf(acc[3][j], 0.f));
        float4 hi = make_float4(fmaxf(acc[4][j], 0.f), fmaxf(acc[5][j], 0.f),
                                fmaxf(acc[6][j], 0.f), fmaxf(acc[7][j], 0.f));
        *(float4*)&sm.ht[c][ty * 8]     = lo;   // one-time write; conflicts negligible
        *(float4*)&sm.ht[c][ty * 8 + 4] = hi;
    }
    __syncthreads();

    // Step 2: z = h @ W2, per-thread rows ty*8+i (8), cols tx*2+j (2)
    float zacc[8][2];
    #pragma unroll
    for (int i = 0; i < 8; ++i) { zacc[i][0] = 0.f; zacc[i][1] = 0.f; }

    for (int k = 0; k < H1; ++k) {
        float4 a0 = *(const float4*)&sm.ht[k][ty * 8];
        float4 a1 = *(const float4*)&sm.ht[k][ty * 8 + 4];
        float2 b  = *(const float2*)&W2[(size_t)k * ZD + tx * 2];
        float a[8] = {a0.x, a0.y, a0.z, a0.w, a1.x, a1.y, a1.z, a1.w};
        #pragma unroll
        for (int i = 0; i < 8; ++i) {
            zacc[i][0] = fmaf(a[i], b.x, zacc[i][0]);
            zacc[i][1] = fmaf(a[i], b.y, zacc[i][1]);
        }
    }
    #pragma unroll
    for (int i = 0; i < 8; ++i) {
        int gr = row0 + ty * 8 + i;
        if (gr < N)
            *(float2*)&Z[(size_t)gr * ZD + tx * 2] =
                make_float2(zacc[i][0], zacc[i][1]);
    }
}

// ---------------------------------------------------------------------------
// decode: out[idx] = sigmoid(dot(z[a], z[b])), 16 lanes per edge (float4 each)
// ---------------------------------------------------------------------------
__global__ __launch_bounds__(256) void decode_kernel(
    const float* __restrict__ Zt, const int* __restrict__ e1,
    const int* __restrict__ e2, float* __restrict__ out, int E)
{
    const int tid  = threadIdx.x;
    const int lane = tid & 63;
    const int wv   = tid >> 6;       // wave in block (0..3)
    const int sub  = lane >> 4;      // edge slot within wave (0..3)
    const int l    = lane & 15;      // lane within edge group
    const int total = 2 * E;
    const int stride = gridDim.x * 16;

    for (int idx = (blockIdx.x * 4 + wv) * 4 + sub; idx < total; idx += stride) {
        const int* ep = (idx < E) ? (e1 + 2 * (size_t)idx)
                                  : (e2 + 2 * (size_t)(idx - E));
        int2 ab = *(const int2*)ep;                 // same addr across 16 lanes -> broadcast
        const float4 va = *(const float4*)&Zt[(size_t)ab.x * ZD + l * 4];
        const float4 vb = *(const float4*)&Zt[(size_t)ab.y * ZD + l * 4];
        float s = va.x * vb.x + va.y * vb.y + va.z * vb.z + va.w * vb.w;
        s += __shfl_xor(s, 8, 64);
        s += __shfl_xor(s, 4, 64);
        s += __shfl_xor(s, 2, 64);
        s += __shfl_xor(s, 1, 64);
        if (l == 0) out[idx] = 1.f / (1.f + __expf(-s));
    }
}

extern "C" void kernel_launch(void* const* d_in, const int* in_sizes, int n_in,
                              void* d_out, int out_size, void* d_ws, size_t ws_size,
                              hipStream_t stream) {
    const float* X  = (const float*)d_in[0];
    const float* W  = (const float*)d_in[1];
    const float* W2 = (const float*)d_in[2];
    const int*   e1 = (const int*)d_in[3];
    const int*   e2 = (const int*)d_in[4];
    float* out = (float*)d_out;
    float* Z   = (float*)d_ws;                 // 100000*64*4 = 25.6 MB scratch

    const int N = in_sizes[0] / IN_DIM;        // 100000
    const int E = in_sizes[3] / 2;             // 1000000

    const int nblk = (N + 63) / 64;
    encode_kernel<<<nblk, 256, 0, stream>>>(X, W, W2, Z, N);

    decode_kernel<<<2048, 256, 0, stream>>>(Z, e1, e2, out, E);
}

// Round 2
// 513.513 us; speedup vs baseline: 1.4096x; 1.4096x over previous
//
#include <hip/hip_runtime.h>
#include <hip/hip_bf16.h>
#include <math.h>

#define IN_DIM 512
#define H1     128
#define ZD     64

typedef __attribute__((ext_vector_type(8))) short bf16x8;
typedef __attribute__((ext_vector_type(4))) float f32x4;

__device__ __forceinline__ ushort f32_to_bf16_bits(float x) {
    unsigned b = __float_as_uint(x);
    unsigned r = (b + 0x7FFF + ((b >> 16) & 1)) >> 16;  // RNE
    return (ushort)r;
}

// ---------------------------------------------------------------------------
// prepack: W (512x128 fp32) -> Whi/Wlo bf16, fragment-linear layout:
//   pack[((s*8 + cb)*64 + lane)*8 + j] = bf16 of W[s*32 + (lane>>4)*8 + j][cb*16 + (lane&15)]
// so a wave's B-frag for (k-step s, col-block cb) is 1KB contiguous.
// ---------------------------------------------------------------------------
__global__ void prepack_w(const float* __restrict__ W,
                          ushort* __restrict__ Whi, ushort* __restrict__ Wlo) {
    int t = blockIdx.x * 256 + threadIdx.x;       // 0..8191
    int s  = t >> 9;
    int cb = (t >> 6) & 7;
    int l  = t & 63;
    ushort h[8], lo[8];
    #pragma unroll
    for (int j = 0; j < 8; ++j) {
        int k   = s * 32 + ((l >> 4) * 8) + j;
        int col = cb * 16 + (l & 15);
        float x = W[(size_t)k * H1 + col];
        ushort hb = f32_to_bf16_bits(x);
        float  hf = __uint_as_float((unsigned)hb << 16);
        h[j]  = hb;
        lo[j] = f32_to_bf16_bits(x - hf);
    }
    size_t off = ((size_t)t) * 8;
    *(ushort4*)&Whi[off]     = make_ushort4(h[0], h[1], h[2], h[3]);
    *(ushort4*)&Whi[off + 4] = make_ushort4(h[4], h[5], h[6], h[7]);
    *(ushort4*)&Wlo[off]     = make_ushort4(lo[0], lo[1], lo[2], lo[3]);
    *(ushort4*)&Wlo[off + 4] = make_ushort4(lo[4], lo[5], lo[6], lo[7]);
}

// ---------------------------------------------------------------------------
// encode: Z = relu(X@W) @ W2
// GEMM1: split-bf16 MFMA (hi*hi + hi*lo + lo*hi), BM=128, BN=128, BK=32.
// 4 waves in 2x2; A staged in LDS fragment-linear (conflict-free b128 reads),
// B frags loaded straight from prepacked global (L2-hot).
// GEMM2: fp32 VALU on LDS-transposed h, two 64-row phases (keeps LDS <= 34KB).
// ---------------------------------------------------------------------------
__global__ __launch_bounds__(256, 2) void encode_kernel(
    const float* __restrict__ X, const ushort* __restrict__ Whi,
    const ushort* __restrict__ Wlo, const float* __restrict__ W2,
    float* __restrict__ Z, int N)
{
    __shared__ __align__(16) union {
        struct { ushort ahi[4096]; ushort alo[4096]; } st;  // 16 KB
        float ht[H1 * 68];                                  // h^T[col][row0..63], 34.8 KB
    } sm;

    const int tid  = threadIdx.x;
    const int lane = tid & 63;
    const int w    = tid >> 6;
    const int wr   = w >> 1;      // row-half of block (0..1)
    const int wc   = w & 1;       // col-half of H1 (0..1)
    const int row0 = blockIdx.x * 128;

    f32x4 acc[4][4];
    #pragma unroll
    for (int i = 0; i < 4; ++i)
        #pragma unroll
        for (int j = 0; j < 4; ++j) acc[i][j] = (f32x4){0.f, 0.f, 0.f, 0.f};

    // register staging of X tile (reg double-buffer across K-steps)
    float4 rg[4];
    #pragma unroll
    for (int t = 0; t < 4; ++t) {
        int idx = tid + t * 256;            // 0..1023
        int row = idx >> 3, k4 = idx & 7;
        int gr  = row0 + row;
        rg[t] = (gr < N) ? *(const float4*)&X[(size_t)gr * IN_DIM + k4 * 4]
                         : make_float4(0.f, 0.f, 0.f, 0.f);
    }

    for (int s = 0; s < 16; ++s) {
        // convert + scatter into fragment-linear LDS (hi/lo)
        #pragma unroll
        for (int t = 0; t < 4; ++t) {
            int idx = tid + t * 256;
            int row = idx >> 3, k4 = idx & 7;
            int rb  = row >> 4;
            int la  = (row & 15) | ((k4 >> 1) << 4);
            int base = rb * 512 + la * 8 + (k4 & 1) * 4;   // ushort units
            float4 v = rg[t];
            ushort h0 = f32_to_bf16_bits(v.x);
            ushort h1 = f32_to_bf16_bits(v.y);
            ushort h2 = f32_to_bf16_bits(v.z);
            ushort h3 = f32_to_bf16_bits(v.w);
            ushort l0 = f32_to_bf16_bits(v.x - __uint_as_float((unsigned)h0 << 16));
            ushort l1 = f32_to_bf16_bits(v.y - __uint_as_float((unsigned)h1 << 16));
            ushort l2 = f32_to_bf16_bits(v.z - __uint_as_float((unsigned)h2 << 16));
            ushort l3 = f32_to_bf16_bits(v.w - __uint_as_float((unsigned)h3 << 16));
            *(ushort4*)&sm.st.ahi[base] = make_ushort4(h0, h1, h2, h3);
            *(ushort4*)&sm.st.alo[base] = make_ushort4(l0, l1, l2, l3);
        }
        __syncthreads();

        // issue next tile's global loads (latency hides under MFMA)
        if (s < 15) {
            #pragma unroll
            for (int t = 0; t < 4; ++t) {
                int idx = tid + t * 256;
                int row = idx >> 3, k4 = idx & 7;
                int gr  = row0 + row;
                rg[t] = (gr < N)
                    ? *(const float4*)&X[(size_t)gr * IN_DIM + (s + 1) * 32 + k4 * 4]
                    : make_float4(0.f, 0.f, 0.f, 0.f);
            }
        }

        // fragments
        bf16x8 aH[4], aL[4], bH[4], bL[4];
        #pragma unroll
        for (int rb = 0; rb < 4; ++rb) {
            int rbg = wr * 4 + rb;
            aH[rb] = *(const bf16x8*)&sm.st.ahi[rbg * 512 + lane * 8];
            aL[rb] = *(const bf16x8*)&sm.st.alo[rbg * 512 + lane * 8];
        }
        #pragma unroll
        for (int cb = 0; cb < 4; ++cb) {
            int cbg = wc * 4 + cb;
            size_t off = ((size_t)(s * 8 + cbg) * 64 + lane) * 8;
            bH[cb] = *(const bf16x8*)&Whi[off];
            bL[cb] = *(const bf16x8*)&Wlo[off];
        }
        #pragma unroll
        for (int rb = 0; rb < 4; ++rb)
            #pragma unroll
            for (int cb = 0; cb < 4; ++cb) {
                acc[rb][cb] = __builtin_amdgcn_mfma_f32_16x16x32_bf16(
                    aH[rb], bH[cb], acc[rb][cb], 0, 0, 0);
                acc[rb][cb] = __builtin_amdgcn_mfma_f32_16x16x32_bf16(
                    aH[rb], bL[cb], acc[rb][cb], 0, 0, 0);
                acc[rb][cb] = __builtin_amdgcn_mfma_f32_16x16x32_bf16(
                    aL[rb], bH[cb], acc[rb][cb], 0, 0, 0);
            }
        __syncthreads();
    }

    // ---- GEMM2 in two 64-row phases: z[r][0..63] = relu(h)[r][:] @ W2 ----
    const int tx = tid & 31;    // col pair: cols tx*2, tx*2+1
    const int ty = tid >> 5;    // row group: rows ty*8 .. ty*8+7 (phase-rel)

    #pragma unroll
    for (int p = 0; p < 2; ++p) {
        if (wr == p) {
            // write relu(h) transposed: ht[col][row_rel], row_rel in 0..63
            #pragma unroll
            for (int rb = 0; rb < 4; ++rb)
                #pragma unroll
                for (int cb = 0; cb < 4; ++cb) {
                    int col = wc * 64 + cb * 16 + (lane & 15);
                    int rr  = rb * 16 + ((lane >> 4) & 3) * 4;
                    #pragma unroll
                    for (int r = 0; r < 4; ++r)
                        sm.ht[col * 68 + rr + r] = fmaxf(acc[rb][cb][r], 0.f);
                }
        }
        __syncthreads();

        float zacc[8][2];
        #pragma unroll
        for (int i = 0; i < 8; ++i) { zacc[i][0] = 0.f; zacc[i][1] = 0.f; }

        #pragma unroll 4
        for (int k = 0; k < H1; ++k) {
            float2 b  = *(const float2*)&W2[(size_t)k * ZD + tx * 2];
            float4 h0 = *(const float4*)&sm.ht[k * 68 + ty * 8];
            float4 h1 = *(const float4*)&sm.ht[k * 68 + ty * 8 + 4];
            float a[8] = {h0.x, h0.y, h0.z, h0.w, h1.x, h1.y, h1.z, h1.w};
            #pragma unroll
            for (int i = 0; i < 8; ++i) {
                zacc[i][0] = fmaf(a[i], b.x, zacc[i][0]);
                zacc[i][1] = fmaf(a[i], b.y, zacc[i][1]);
            }
        }
        #pragma unroll
        for (int i = 0; i < 8; ++i) {
            int gr = row0 + p * 64 + ty * 8 + i;
            if (gr < N)
                *(float2*)&Z[(size_t)gr * ZD + tx * 2] =
                    make_float2(zacc[i][0], zacc[i][1]);
        }
        __syncthreads();
    }
}

// ---------------------------------------------------------------------------
// decode: out[idx] = sigmoid(dot(z[a], z[b])), 16 lanes per edge (float4 each)
// ---------------------------------------------------------------------------
__global__ __launch_bounds__(256) void decode_kernel(
    const float* __restrict__ Zt, const int* __restrict__ e1,
    const int* __restrict__ e2, float* __restrict__ out, int E)
{
    const int tid  = threadIdx.x;
    const int lane = tid & 63;
    const int wv   = tid >> 6;
    const int sub  = lane >> 4;
    const int l    = lane & 15;
    const int total = 2 * E;
    const int stride = gridDim.x * 16;

    for (int idx = (blockIdx.x * 4 + wv) * 4 + sub; idx < total; idx += stride) {
        const int* ep = (idx < E) ? (e1 + 2 * (size_t)idx)
                                  : (e2 + 2 * (size_t)(idx - E));
        int2 ab = *(const int2*)ep;
        const float4 va = *(const float4*)&Zt[(size_t)ab.x * ZD + l * 4];
        const float4 vb = *(const float4*)&Zt[(size_t)ab.y * ZD + l * 4];
        float s = va.x * vb.x + va.y * vb.y + va.z * vb.z + va.w * vb.w;
        s += __shfl_xor(s, 8, 64);
        s += __shfl_xor(s, 4, 64);
        s += __shfl_xor(s, 2, 64);
        s += __shfl_xor(s, 1, 64);
        if (l == 0) out[idx] = 1.f / (1.f + __expf(-s));
    }
}

extern "C" void kernel_launch(void* const* d_in, const int* in_sizes, int n_in,
                              void* d_out, int out_size, void* d_ws, size_t ws_size,
                              hipStream_t stream) {
    const float* X  = (const float*)d_in[0];
    const float* W  = (const float*)d_in[1];
    const float* W2 = (const float*)d_in[2];
    const int*   e1 = (const int*)d_in[3];
    const int*   e2 = (const int*)d_in[4];
    float* out = (float*)d_out;

    const int N = in_sizes[0] / IN_DIM;        // 100000
    const int E = in_sizes[3] / 2;             // 1000000

    float*  Z   = (float*)d_ws;                               // 25.6 MB
    ushort* Whi = (ushort*)((char*)d_ws + 25600000);          // 128 KB
    ushort* Wlo = (ushort*)((char*)d_ws + 25600000 + 131072); // 128 KB

    prepack_w<<<32, 256, 0, stream>>>(W, Whi, Wlo);

    const int nblk = (N + 127) / 128;
    encode_kernel<<<nblk, 256, 0, stream>>>(X, Whi, Wlo, W2, Z, N);

    decode_kernel<<<2048, 256, 0, stream>>>(Z, e1, e2, out, E);
}

// Round 3
// 398.024 us; speedup vs baseline: 1.8186x; 1.2902x over previous
//
#include <hip/hip_runtime.h>
#include <hip/hip_bf16.h>
#include <hip/hip_fp16.h>
#include <math.h>

#define IN_DIM 512
#define H1     128
#define ZD     64

typedef __attribute__((ext_vector_type(8))) short bf16x8;
typedef __attribute__((ext_vector_type(4))) float f32x4;

__device__ __forceinline__ ushort f32_to_bf16_bits(float x) {
    unsigned b = __float_as_uint(x);
    unsigned r = (b + 0x7FFF + ((b >> 16) & 1)) >> 16;  // RNE
    return (ushort)r;
}

// ---------------------------------------------------------------------------
// prepack: W (512x128 fp32) -> Whi/Wlo bf16, fragment-linear layout:
//   pack[((s*8 + cb)*64 + lane)*8 + j] = bf16 of W[s*32 + (lane>>4)*8 + j][cb*16 + (lane&15)]
// ---------------------------------------------------------------------------
__global__ void prepack_w(const float* __restrict__ W,
                          ushort* __restrict__ Whi, ushort* __restrict__ Wlo) {
    int t = blockIdx.x * 256 + threadIdx.x;       // 0..8191
    int s  = t >> 9;
    int cb = (t >> 6) & 7;
    int l  = t & 63;
    ushort h[8], lo[8];
    #pragma unroll
    for (int j = 0; j < 8; ++j) {
        int k   = s * 32 + ((l >> 4) * 8) + j;
        int col = cb * 16 + (l & 15);
        float x = W[(size_t)k * H1 + col];
        ushort hb = f32_to_bf16_bits(x);
        float  hf = __uint_as_float((unsigned)hb << 16);
        h[j]  = hb;
        lo[j] = f32_to_bf16_bits(x - hf);
    }
    size_t off = ((size_t)t) * 8;
    *(ushort4*)&Whi[off]     = make_ushort4(h[0], h[1], h[2], h[3]);
    *(ushort4*)&Whi[off + 4] = make_ushort4(h[4], h[5], h[6], h[7]);
    *(ushort4*)&Wlo[off]     = make_ushort4(lo[0], lo[1], lo[2], lo[3]);
    *(ushort4*)&Wlo[off + 4] = make_ushort4(lo[4], lo[5], lo[6], lo[7]);
}

// ---------------------------------------------------------------------------
// encode: Z = relu(X@W) @ W2   (Z stored fp16)
// GEMM1: split-bf16 MFMA (hi*hi + hi*lo + lo*hi), BM=64, BN=128, BK=32,
//        double-buffered LDS, ONE barrier per K-step.
// 4 waves 2x2: wr = rows 32*wr.., wc = cols 64*wc..
// GEMM2: fp32 VALU on LDS-transposed h (K=128), output fp16.
// ---------------------------------------------------------------------------
__global__ __launch_bounds__(256, 4) void encode_kernel(
    const float* __restrict__ X, const ushort* __restrict__ Whi,
    const ushort* __restrict__ Wlo, const float* __restrict__ W2,
    __half* __restrict__ Z, int N)
{
    __shared__ __align__(16) union {
        ushort st[2][2][4][512];   // [buf][hi/lo][rb][lane*8+j]  16 KB
        float  ht[H1][68];         // h^T[col][row], 34.8 KB
    } sm;

    const int tid  = threadIdx.x;
    const int lane = tid & 63;
    const int w    = tid >> 6;
    const int wr   = w >> 1;
    const int wc   = w & 1;
    const int row0 = blockIdx.x * 64;

    // staging mapping: row = tid>>2 (0..63), kq = tid&3 (8-k chunk)
    const int srow = tid >> 2;
    const int kq   = tid & 3;
    const int srb  = srow >> 4;
    const int sla  = (srow & 15) | (kq << 4);
    const bool srow_ok = (row0 + srow) < N;
    const float* xp = X + (size_t)(row0 + srow) * IN_DIM + kq * 8;

    f32x4 acc[2][4];
    #pragma unroll
    for (int i = 0; i < 2; ++i)
        #pragma unroll
        for (int j = 0; j < 4; ++j) acc[i][j] = (f32x4){0.f, 0.f, 0.f, 0.f};

    float4 rgA, rgB;
    rgA = srow_ok ? *(const float4*)(xp + 0) : make_float4(0, 0, 0, 0);
    rgB = srow_ok ? *(const float4*)(xp + 4) : make_float4(0, 0, 0, 0);

    // convert + write to buf (trunc split: hi = x&0xFFFF0000, lo = exact residual)
    auto stage = [&](int buf) {
        float xv[8] = {rgA.x, rgA.y, rgA.z, rgA.w, rgB.x, rgB.y, rgB.z, rgB.w};
        unsigned hb[8], lb[8];
        #pragma unroll
        for (int j = 0; j < 8; ++j) {
            unsigned b = __float_as_uint(xv[j]);
            unsigned hf = b & 0xFFFF0000u;
            hb[j] = b;
            lb[j] = __float_as_uint(xv[j] - __uint_as_float(hf));
        }
        uint4 hp, lp;
        hp.x = (hb[0] >> 16) | (hb[1] & 0xFFFF0000u);
        hp.y = (hb[2] >> 16) | (hb[3] & 0xFFFF0000u);
        hp.z = (hb[4] >> 16) | (hb[5] & 0xFFFF0000u);
        hp.w = (hb[6] >> 16) | (hb[7] & 0xFFFF0000u);
        lp.x = (lb[0] >> 16) | (lb[1] & 0xFFFF0000u);
        lp.y = (lb[2] >> 16) | (lb[3] & 0xFFFF0000u);
        lp.z = (lb[4] >> 16) | (lb[5] & 0xFFFF0000u);
        lp.w = (lb[6] >> 16) | (lb[7] & 0xFFFF0000u);
        *(uint4*)&sm.st[buf][0][srb][sla * 8] = hp;
        *(uint4*)&sm.st[buf][1][srb][sla * 8] = lp;
    };

    stage(0);
    rgA = srow_ok ? *(const float4*)(xp + 32) : make_float4(0, 0, 0, 0);
    rgB = srow_ok ? *(const float4*)(xp + 36) : make_float4(0, 0, 0, 0);
    __syncthreads();

    for (int s = 0; s < 16; ++s) {
        const int buf = s & 1;
        // A fragments (conflict-free contiguous 1KB reads)
        bf16x8 aH[2], aL[2];
        #pragma unroll
        for (int rb = 0; rb < 2; ++rb) {
            int rbg = wr * 2 + rb;
            aH[rb] = *(const bf16x8*)&sm.st[buf][0][rbg][lane * 8];
            aL[rb] = *(const bf16x8*)&sm.st[buf][1][rbg][lane * 8];
        }
        // stage next tile (rg holds s+1 data), then issue s+2 loads
        if (s < 15) stage(buf ^ 1);
        if (s < 14) {
            const float* xp2 = xp + (s + 2) * 32;
            rgA = srow_ok ? *(const float4*)(xp2 + 0) : make_float4(0, 0, 0, 0);
            rgB = srow_ok ? *(const float4*)(xp2 + 4) : make_float4(0, 0, 0, 0);
        }
        // B fragments straight from L2 + MFMA
        #pragma unroll
        for (int cb = 0; cb < 4; ++cb) {
            int cbg = wc * 4 + cb;
            size_t off = ((size_t)(s * 8 + cbg) * 64 + lane) * 8;
            bf16x8 bH = *(const bf16x8*)&Whi[off];
            bf16x8 bL = *(const bf16x8*)&Wlo[off];
            #pragma unroll
            for (int rb = 0; rb < 2; ++rb) {
                acc[rb][cb] = __builtin_amdgcn_mfma_f32_16x16x32_bf16(
                    aH[rb], bH, acc[rb][cb], 0, 0, 0);
                acc[rb][cb] = __builtin_amdgcn_mfma_f32_16x16x32_bf16(
                    aH[rb], bL, acc[rb][cb], 0, 0, 0);
                acc[rb][cb] = __builtin_amdgcn_mfma_f32_16x16x32_bf16(
                    aL[rb], bH, acc[rb][cb], 0, 0, 0);
            }
        }
        __syncthreads();
    }

    // ---- write relu(h) transposed: ht[col][row_local] ----
    #pragma unroll
    for (int rb = 0; rb < 2; ++rb)
        #pragma unroll
        for (int cb = 0; cb < 4; ++cb) {
            int col = wc * 64 + cb * 16 + (lane & 15);
            int rr  = wr * 32 + rb * 16 + (lane >> 4) * 4;
            #pragma unroll
            for (int r = 0; r < 4; ++r)
                sm.ht[col][rr + r] = fmaxf(acc[rb][cb][r], 0.f);
        }
    __syncthreads();

    // ---- GEMM2: z[r][c] = relu(h)[r][:] @ W2, K=128 ----
    const int tx = tid & 31;
    const int ty = tid >> 5;

    float zacc[8][2];
    #pragma unroll
    for (int i = 0; i < 8; ++i) { zacc[i][0] = 0.f; zacc[i][1] = 0.f; }

    #pragma unroll 4
    for (int k = 0; k < H1; ++k) {
        float2 b  = *(const float2*)&W2[(size_t)k * ZD + tx * 2];
        float4 h0 = *(const float4*)&sm.ht[k][ty * 8];
        float4 h1 = *(const float4*)&sm.ht[k][ty * 8 + 4];
        float a[8] = {h0.x, h0.y, h0.z, h0.w, h1.x, h1.y, h1.z, h1.w};
        #pragma unroll
        for (int i = 0; i < 8; ++i) {
            zacc[i][0] = fmaf(a[i], b.x, zacc[i][0]);
            zacc[i][1] = fmaf(a[i], b.y, zacc[i][1]);
        }
    }
    #pragma unroll
    for (int i = 0; i < 8; ++i) {
        int gr = row0 + ty * 8 + i;
        if (gr < N)
            *(__half2*)&Z[(size_t)gr * ZD + tx * 2] =
                __floats2half2_rn(zacc[i][0], zacc[i][1]);
    }
}

// ---------------------------------------------------------------------------
// decode: out[idx] = sigmoid(dot(z[a], z[b])), fp16 z, 8 lanes/edge (16B each)
// ---------------------------------------------------------------------------
__global__ __launch_bounds__(256) void decode_kernel(
    const __half* __restrict__ Zh, const int* __restrict__ e1,
    const int* __restrict__ e2, float* __restrict__ out, int E)
{
    const int tid  = threadIdx.x;
    const int lane = tid & 63;
    const int wv   = tid >> 6;
    const int sub  = lane >> 3;      // 8 edges per wave
    const int l    = lane & 7;       // lane within edge group
    const int total = 2 * E;
    const int stride = gridDim.x * 32;

    for (int idx = (blockIdx.x * 4 + wv) * 8 + sub; idx < total; idx += stride) {
        const int* ep = (idx < E) ? (e1 + 2 * (size_t)idx)
                                  : (e2 + 2 * (size_t)(idx - E));
        int2 ab = *(const int2*)ep;                 // broadcast across 8 lanes
        union { uint4 u; __half2 h[4]; } A, B;
        A.u = *(const uint4*)&Zh[(size_t)ab.x * ZD + l * 8];
        B.u = *(const uint4*)&Zh[(size_t)ab.y * ZD + l * 8];
        float s = 0.f;
        #pragma unroll
        for (int j = 0; j < 4; ++j) {
            float2 fa = __half22float2(A.h[j]);
            float2 fb = __half22float2(B.h[j]);
            s += fa.x * fb.x + fa.y * fb.y;
        }
        s += __shfl_xor(s, 4, 64);
        s += __shfl_xor(s, 2, 64);
        s += __shfl_xor(s, 1, 64);
        if (l == 0) out[idx] = 1.f / (1.f + __expf(-s));
    }
}

extern "C" void kernel_launch(void* const* d_in, const int* in_sizes, int n_in,
                              void* d_out, int out_size, void* d_ws, size_t ws_size,
                              hipStream_t stream) {
    const float* X  = (const float*)d_in[0];
    const float* W  = (const float*)d_in[1];
    const float* W2 = (const float*)d_in[2];
    const int*   e1 = (const int*)d_in[3];
    const int*   e2 = (const int*)d_in[4];
    float* out = (float*)d_out;

    const int N = in_sizes[0] / IN_DIM;        // 100000
    const int E = in_sizes[3] / 2;             // 1000000

    __half* Zh  = (__half*)d_ws;                               // 12.8 MB
    ushort* Whi = (ushort*)((char*)d_ws + 12800000);           // 128 KB
    ushort* Wlo = (ushort*)((char*)d_ws + 12800000 + 131072);  // 128 KB

    prepack_w<<<32, 256, 0, stream>>>(W, Whi, Wlo);

    const int nblk = (N + 63) / 64;
    encode_kernel<<<nblk, 256, 0, stream>>>(X, Whi, Wlo, W2, Zh, N);

    decode_kernel<<<2048, 256, 0, stream>>>(Zh, e1, e2, out, E);
}